// Round 2
// baseline (498.385 us; speedup 1.0000x reference)
//
#include <hip/hip_runtime.h>
#include <stdint.h>

#define NN 256
#define BATCH 262144

typedef unsigned short ushort_t;
typedef __attribute__((ext_vector_type(8))) short short8_t;
typedef __attribute__((ext_vector_type(4))) float f32x4;

__device__ __forceinline__ ushort_t f2bf(float f) {
  // round-to-nearest-even float -> bf16 (values are finite; no NaN handling needed)
  uint32_t u = __float_as_uint(f);
  u += 0x7fffu + ((u >> 16) & 1u);
  return (ushort_t)(u >> 16);
}

// ---------------- K1: M = W^T W (fp32) ----------------
__global__ __launch_bounds__(256) void gram_kernel(const float* __restrict__ W,
                                                   float* __restrict__ M) {
  int bi = blockIdx.x >> 4, bj = blockIdx.x & 15;
  int ti = threadIdx.x >> 4, tj = threadIdx.x & 15;
  int i = bi * 16 + ti, j = bj * 16 + tj;
  float acc = 0.f;
#pragma unroll 8
  for (int k = 0; k < NN; ++k) acc += W[k * NN + i] * W[k * NN + j];
  M[i * NN + j] = acc;
}

// ---------------- K1b/K1c: C = A*A (fp32) ----------------
__global__ __launch_bounds__(256) void matsq_kernel(const float* __restrict__ A,
                                                    float* __restrict__ C) {
  int bi = blockIdx.x >> 4, bj = blockIdx.x & 15;
  int ti = threadIdx.x >> 4, tj = threadIdx.x & 15;
  int i = bi * 16 + ti, j = bj * 16 + tj;
  float acc = 0.f;
#pragma unroll 8
  for (int k = 0; k < NN; ++k) acc += A[i * NN + k] * A[k * NN + j];
  C[i * NN + j] = acc;
}

// ---------------- K2: v = (M4)^5 v0 ; sigma = sqrt(v^T M v / v^T v); emit Wz ----------------
// Wz layout (bf16, ushort): physical chunk (16B = 8 elems) at
//   wz[kt*8192 + n*32 + kqs*8], kqs = kq ^ ((n>>1)&3), holding Wz[n][kt*32 + kq*8 .. +7]
__global__ __launch_bounds__(1024) void power_kernel(const float* __restrict__ W,
                                                     const float* __restrict__ M,
                                                     const float* __restrict__ M4,
                                                     ushort_t* __restrict__ wz) {
  __shared__ float v_lds[NN];
  __shared__ float psum[4 * NN];
  __shared__ float red[16];
  __shared__ float scale_s;
  const int t = threadIdx.x;
  const int r = t >> 2, qc = t & 3;  // thread owns M4[r][j*16 + qc*4 .. +3], j=0..15

  f32x4 Mreg[16];
#pragma unroll
  for (int j = 0; j < 16; ++j)
    Mreg[j] = *(const f32x4*)(M4 + r * NN + j * 16 + qc * 4);

  if (t < NN) v_lds[t] = 0.0625f;  // 1/sqrt(256)
  __syncthreads();

  for (int it = 0; it < 5; ++it) {  // (M^4)^5 = M^20
    float p = 0.f;
#pragma unroll
    for (int j = 0; j < 16; ++j) {
      f32x4 v4 = *(const f32x4*)(v_lds + j * 16 + qc * 4);
      p += Mreg[j].x * v4.x + Mreg[j].y * v4.y + Mreg[j].z * v4.z + Mreg[j].w * v4.w;
    }
    psum[qc * NN + r] = p;
    __syncthreads();
    if (t < NN)
      v_lds[t] = psum[t] + psum[NN + t] + psum[2 * NN + t] + psum[3 * NN + t];
    __syncthreads();
  }

  {  // sigma^2 = v^T M v / v^T v   (M = W^T W, so this is ||W v_hat||^2)
    float p = 0.f;
#pragma unroll
    for (int j = 0; j < 16; ++j) {
      f32x4 m4 = *(const f32x4*)(M + r * NN + j * 16 + qc * 4);
      f32x4 v4 = *(const f32x4*)(v_lds + j * 16 + qc * 4);
      p += m4.x * v4.x + m4.y * v4.y + m4.z * v4.z + m4.w * v4.w;
    }
    psum[qc * NN + r] = p;
    __syncthreads();
    float num = 0.f, den = 0.f;
    if (t < NN) {
      float y = psum[t] + psum[NN + t] + psum[2 * NN + t] + psum[3 * NN + t];
      float v = v_lds[t];
      num = v * y;
      den = v * v;
    }
#pragma unroll
    for (int off = 32; off > 0; off >>= 1) {
      num += __shfl_down(num, off);
      den += __shfl_down(den, off);
    }
    if (t < NN && (t & 63) == 0) {
      red[(t >> 6) * 2] = num;
      red[(t >> 6) * 2 + 1] = den;
    }
    __syncthreads();
    if (t == 0) {
      float n = red[0] + red[2] + red[4] + red[6];
      float d = red[1] + red[3] + red[5] + red[7];
      float sig = sqrtf(n / d) + 1e-12f;
      scale_s = 1.0f / sig;  // LIP_CONSTANT = 1
    }
    __syncthreads();
  }
  const float scale = scale_s;

  // Wz = (W * scale) with zero diagonal, bf16, swizzled for GEMM B-operand
  for (int o = t; o < 8192; o += 1024) {
    int n = o >> 5;
    int koct = o & 31;
    int k0 = koct * 8;
    int kt = koct >> 2, kq = koct & 3;
    int kqs = kq ^ ((n >> 1) & 3);
    f32x4 a = *(const f32x4*)(W + n * NN + k0);
    f32x4 b = *(const f32x4*)(W + n * NN + k0 + 4);
    float f[8] = {a.x, a.y, a.z, a.w, b.x, b.y, b.z, b.w};
    short8_t pack;
#pragma unroll
    for (int e = 0; e < 8; ++e) {
      float val = (n == k0 + e) ? 0.f : f[e] * scale;
      pack[e] = (short)f2bf(val);
    }
    *(short8_t*)(wz + kt * 8192 + n * 32 + kqs * 8) = pack;
  }
}

// ---------------- K3: out = x @ Wz^T  (bf16 MFMA, fp32 out) ----------------
// BM=64, BN=256 (full N -> x read exactly once), BK=32, 256 threads / 4 waves.
// Wave w computes 64 x 64 (cols w*64..): 4x4 grid of 16x16x32 MFMAs per k-step.
// Pipelined double-buffered LDS (neutral vs 2-barrier, kept).
// LDS = 40960 B exactly -> 4 blocks/CU fit in 160 KiB; __launch_bounds__(256,4)
// caps VGPR at 128 so occupancy is 4 blocks (16 waves)/CU for +33% in-flight
// memory (TLP-limited-BW hypothesis). unroll 2 keeps address-hoisting pressure
// under the 128-VGPR cap (acc alone = 64 VGPRs).
__global__ __launch_bounds__(256, 4) void gemm_kernel(const float* __restrict__ x,
                                                      const ushort_t* __restrict__ wz,
                                                      float* __restrict__ out) {
  __shared__ __align__(16) ushort_t lsA[2][64 * 32];   // 2 x 4 KB, swizzled chunks
  __shared__ __align__(16) ushort_t lsB[2][256 * 32];  // 2 x 16 KB, swizzled chunks
  const int tid = threadIdx.x;
  const int wave = tid >> 6, lane = tid & 63;
  const int m0 = blockIdx.x * 64;
  const int m = lane & 15, q = lane >> 4;
  const int sw = (m >> 1) & 3;

  f32x4 acc[4][4];
  const f32x4 zero = {0.f, 0.f, 0.f, 0.f};
#pragma unroll
  for (int a = 0; a < 4; ++a)
#pragma unroll
    for (int b = 0; b < 4; ++b) acc[a][b] = zero;

  // A staging: thread -> (row ar, k-octet ak); coalesced 128B global segments
  const int ar = tid >> 2;
  const int ak = tid & 3;
  const int achunk = ar * 4 + (ak ^ ((ar >> 1) & 3));  // XOR swizzle: <=2-way banks
  const float* aptr = x + (m0 + ar) * NN + ak * 8;

  // ---- prologue: stage tile 0 into buffer 0 ----
  {
    f32x4 c0 = *(const f32x4*)(aptr);
    f32x4 c1 = *(const f32x4*)(aptr + 4);
#pragma unroll
    for (int i = 0; i < 4; ++i) {
      const int cbase = i * 256 + wave * 64;  // wave-uniform LDS base
      __builtin_amdgcn_global_load_lds(
          (const __attribute__((address_space(1))) uint32_t*)(wz + (cbase + lane) * 8),
          (__attribute__((address_space(3))) uint32_t*)(&lsB[0][cbase * 8]), 16, 0, 0);
    }
    short8_t av;
    av[0] = (short)f2bf(c0.x); av[1] = (short)f2bf(c0.y);
    av[2] = (short)f2bf(c0.z); av[3] = (short)f2bf(c0.w);
    av[4] = (short)f2bf(c1.x); av[5] = (short)f2bf(c1.y);
    av[6] = (short)f2bf(c1.z); av[7] = (short)f2bf(c1.w);
    *(short8_t*)(&lsA[0][achunk * 8]) = av;
    __syncthreads();
  }

#pragma unroll 2
  for (int kt = 0; kt < 8; ++kt) {
    const int cur = kt & 1, nxt = cur ^ 1;

    // ---- issue tile kt+1 (A: global->reg fp32; B: async global->LDS) ----
    f32x4 c0, c1;
    if (kt < 7) {
      c0 = *(const f32x4*)(aptr + (kt + 1) * 32);
      c1 = *(const f32x4*)(aptr + (kt + 1) * 32 + 4);
#pragma unroll
      for (int i = 0; i < 4; ++i) {
        const int cbase = i * 256 + wave * 64;  // wave-uniform LDS base
        __builtin_amdgcn_global_load_lds(
            (const __attribute__((address_space(1))) uint32_t*)(wz + (kt + 1) * 8192 +
                                                                (cbase + lane) * 8),
            (__attribute__((address_space(3))) uint32_t*)(&lsB[nxt][cbase * 8]), 16, 0,
            0);
      }
    }

    // ---- compute tile kt from buffer cur ----
    short8_t af[4], bfrag[4];
#pragma unroll
    for (int mt = 0; mt < 4; ++mt) {
      int c = (mt * 16 + m) * 4 + (q ^ sw);
      af[mt] = *(const short8_t*)(&lsA[cur][c * 8]);
    }
#pragma unroll
    for (int nt = 0; nt < 4; ++nt) {
      int c = (wave * 64 + nt * 16 + m) * 4 + (q ^ sw);
      bfrag[nt] = *(const short8_t*)(&lsB[cur][c * 8]);
    }
#pragma unroll
    for (int mt = 0; mt < 4; ++mt)
#pragma unroll
      for (int nt = 0; nt < 4; ++nt)
        acc[mt][nt] = __builtin_amdgcn_mfma_f32_16x16x32_bf16(af[mt], bfrag[nt],
                                                              acc[mt][nt], 0, 0, 0);

    // ---- finish staging tile kt+1 (convert A after MFMAs), single barrier ----
    if (kt < 7) {
      short8_t av;
      av[0] = (short)f2bf(c0.x); av[1] = (short)f2bf(c0.y);
      av[2] = (short)f2bf(c0.z); av[3] = (short)f2bf(c0.w);
      av[4] = (short)f2bf(c1.x); av[5] = (short)f2bf(c1.y);
      av[6] = (short)f2bf(c1.z); av[7] = (short)f2bf(c1.w);
      *(short8_t*)(&lsA[nxt][achunk * 8]) = av;
      __syncthreads();
    }
  }

  // epilogue: C/D layout col=lane&15, row=quad*4+reg
#pragma unroll
  for (int mt = 0; mt < 4; ++mt) {
#pragma unroll
    for (int nt = 0; nt < 4; ++nt) {
      const int col = wave * 64 + nt * 16 + m;
      const int rowb = m0 + mt * 16 + q * 4;
#pragma unroll
      for (int e = 0; e < 4; ++e) out[(rowb + e) * NN + col] = acc[mt][nt][e];
    }
  }
}

extern "C" void kernel_launch(void* const* d_in, const int* in_sizes, int n_in,
                              void* d_out, int out_size, void* d_ws, size_t ws_size,
                              hipStream_t stream) {
  const float* x = (const float*)d_in[0];
  const float* W = (const float*)d_in[1];
  float* out = (float*)d_out;

  char* ws = (char*)d_ws;
  ushort_t* wz = (ushort_t*)ws;                       // 131072 B (bf16 Wz, swizzled)
  float* M = (float*)(ws + 131072);                   // 262144 B
  float* M2 = (float*)(ws + 131072 + 262144);         // 262144 B
  float* M4 = (float*)(ws + 131072 + 2 * 262144);     // 262144 B

  gram_kernel<<<256, 256, 0, stream>>>(W, M);
  matsq_kernel<<<256, 256, 0, stream>>>(M, M2);
  matsq_kernel<<<256, 256, 0, stream>>>(M2, M4);
  power_kernel<<<1, 1024, 0, stream>>>(W, M, M4, wz);
  gemm_kernel<<<BATCH / 64, 256, 0, stream>>>(x, wz, out);
}

// Round 4
// 488.016 us; speedup vs baseline: 1.0212x; 1.0212x over previous
//
#include <hip/hip_runtime.h>
#include <stdint.h>

#define NN 256
#define BATCH 262144

typedef unsigned short ushort_t;
typedef __attribute__((ext_vector_type(8))) short short8_t;
typedef __attribute__((ext_vector_type(4))) float f32x4;

__device__ __forceinline__ ushort_t f2bf(float f) {
  // round-to-nearest-even float -> bf16 (values are finite; no NaN handling needed)
  uint32_t u = __float_as_uint(f);
  u += 0x7fffu + ((u >> 16) & 1u);
  return (ushort_t)(u >> 16);
}

// ---------------- K1: M = W^T W (fp32) ----------------
__global__ __launch_bounds__(256) void gram_kernel(const float* __restrict__ W,
                                                   float* __restrict__ M) {
  int bi = blockIdx.x >> 4, bj = blockIdx.x & 15;
  int ti = threadIdx.x >> 4, tj = threadIdx.x & 15;
  int i = bi * 16 + ti, j = bj * 16 + tj;
  float acc = 0.f;
#pragma unroll 8
  for (int k = 0; k < NN; ++k) acc += W[k * NN + i] * W[k * NN + j];
  M[i * NN + j] = acc;
}

// ---------------- K2: v = M^20 v0 ; sigma = sqrt(v^T M v / v^T v); emit Wz ----------------
// M held in registers (16 x f32x4 per thread); 20 unnormalized matvec iterations
// == (M^4)^5 of the previous version (growth ~sigma(M)^20 ~ 1e12, fp32-safe).
// Wz layout (bf16, ushort): physical chunk (16B = 8 elems) at
//   wz[kt*8192 + n*32 + kqs*8], kqs = kq ^ ((n>>1)&3), holding Wz[n][kt*32 + kq*8 .. +7]
__global__ __launch_bounds__(1024) void power_kernel(const float* __restrict__ W,
                                                     const float* __restrict__ M,
                                                     ushort_t* __restrict__ wz) {
  __shared__ float v_lds[NN];
  __shared__ float psum[4 * NN];
  __shared__ float red[16];
  __shared__ float scale_s;
  const int t = threadIdx.x;
  const int r = t >> 2, qc = t & 3;  // thread owns M[r][j*16 + qc*4 .. +3], j=0..15

  f32x4 Mreg[16];
#pragma unroll
  for (int j = 0; j < 16; ++j)
    Mreg[j] = *(const f32x4*)(M + r * NN + j * 16 + qc * 4);

  if (t < NN) v_lds[t] = 0.0625f;  // 1/sqrt(256)
  __syncthreads();

  for (int it = 0; it < 20; ++it) {  // v <- M^20 v0
    float p = 0.f;
#pragma unroll
    for (int j = 0; j < 16; ++j) {
      f32x4 v4 = *(const f32x4*)(v_lds + j * 16 + qc * 4);
      p += Mreg[j].x * v4.x + Mreg[j].y * v4.y + Mreg[j].z * v4.z + Mreg[j].w * v4.w;
    }
    psum[qc * NN + r] = p;
    __syncthreads();
    if (t < NN)
      v_lds[t] = psum[t] + psum[NN + t] + psum[2 * NN + t] + psum[3 * NN + t];
    __syncthreads();
  }

  {  // sigma^2 = v^T M v / v^T v   (M = W^T W, so this is ||W v_hat||^2)
    float p = 0.f;
#pragma unroll
    for (int j = 0; j < 16; ++j) {
      f32x4 v4 = *(const f32x4*)(v_lds + j * 16 + qc * 4);
      p += Mreg[j].x * v4.x + Mreg[j].y * v4.y + Mreg[j].z * v4.z + Mreg[j].w * v4.w;
    }
    psum[qc * NN + r] = p;
    __syncthreads();
    float num = 0.f, den = 0.f;
    if (t < NN) {
      float y = psum[t] + psum[NN + t] + psum[2 * NN + t] + psum[3 * NN + t];
      float v = v_lds[t];
      num = v * y;
      den = v * v;
    }
#pragma unroll
    for (int off = 32; off > 0; off >>= 1) {
      num += __shfl_down(num, off);
      den += __shfl_down(den, off);
    }
    if (t < NN && (t & 63) == 0) {
      red[(t >> 6) * 2] = num;
      red[(t >> 6) * 2 + 1] = den;
    }
    __syncthreads();
    if (t == 0) {
      float n = red[0] + red[2] + red[4] + red[6];
      float d = red[1] + red[3] + red[5] + red[7];
      float sig = sqrtf(n / d) + 1e-12f;
      scale_s = 1.0f / sig;  // LIP_CONSTANT = 1
    }
    __syncthreads();
  }
  const float scale = scale_s;

  // Wz = (W * scale) with zero diagonal, bf16, swizzled for GEMM B-operand
  for (int o = t; o < 8192; o += 1024) {
    int n = o >> 5;
    int koct = o & 31;
    int k0 = koct * 8;
    int kt = koct >> 2, kq = koct & 3;
    int kqs = kq ^ ((n >> 1) & 3);
    f32x4 a = *(const f32x4*)(W + n * NN + k0);
    f32x4 b = *(const f32x4*)(W + n * NN + k0 + 4);
    float f[8] = {a.x, a.y, a.z, a.w, b.x, b.y, b.z, b.w};
    short8_t pack;
#pragma unroll
    for (int e = 0; e < 8; ++e) {
      float val = (n == k0 + e) ? 0.f : f[e] * scale;
      pack[e] = (short)f2bf(val);
    }
    *(short8_t*)(wz + kt * 8192 + n * 32 + kqs * 8) = pack;
  }
}

// ---------------- K3: out = x @ Wz^T  (bf16 MFMA, fp32 out) ----------------
// BM=64, BN=256 (full N -> x read exactly once), BK=32, 256 threads / 4 waves.
// Wave w computes 64 x 64 (cols w*64..): 4x4 grid of 16x16x32 MFMAs per k-step.
// Pipelined double-buffered LDS. BW-saturated: pipelining (r1) and 4-block
// occupancy (r2) both neutral -> keep best-measured config (256,3).
__global__ __launch_bounds__(256, 3) void gemm_kernel(const float* __restrict__ x,
                                                      const ushort_t* __restrict__ wz,
                                                      float* __restrict__ out) {
  __shared__ __align__(16) ushort_t lsA[2][64 * 32];   // 2 x 4 KB, swizzled chunks
  __shared__ __align__(16) ushort_t lsB[2][256 * 32];  // 2 x 16 KB, swizzled chunks
  const int tid = threadIdx.x;
  const int wave = tid >> 6, lane = tid & 63;
  const int m0 = blockIdx.x * 64;
  const int m = lane & 15, q = lane >> 4;
  const int sw = (m >> 1) & 3;

  f32x4 acc[4][4];
  const f32x4 zero = {0.f, 0.f, 0.f, 0.f};
#pragma unroll
  for (int a = 0; a < 4; ++a)
#pragma unroll
    for (int b = 0; b < 4; ++b) acc[a][b] = zero;

  // A staging: thread -> (row ar, k-octet ak); coalesced 128B global segments
  const int ar = tid >> 2;
  const int ak = tid & 3;
  const int achunk = ar * 4 + (ak ^ ((ar >> 1) & 3));  // XOR swizzle: <=2-way banks
  const float* aptr = x + (m0 + ar) * NN + ak * 8;

  // ---- prologue: stage tile 0 into buffer 0 ----
  {
    f32x4 c0 = *(const f32x4*)(aptr);
    f32x4 c1 = *(const f32x4*)(aptr + 4);
#pragma unroll
    for (int i = 0; i < 4; ++i) {
      const int cbase = i * 256 + wave * 64;  // wave-uniform LDS base
      __builtin_amdgcn_global_load_lds(
          (const __attribute__((address_space(1))) uint32_t*)(wz + (cbase + lane) * 8),
          (__attribute__((address_space(3))) uint32_t*)(&lsB[0][cbase * 8]), 16, 0, 0);
    }
    short8_t av;
    av[0] = (short)f2bf(c0.x); av[1] = (short)f2bf(c0.y);
    av[2] = (short)f2bf(c0.z); av[3] = (short)f2bf(c0.w);
    av[4] = (short)f2bf(c1.x); av[5] = (short)f2bf(c1.y);
    av[6] = (short)f2bf(c1.z); av[7] = (short)f2bf(c1.w);
    *(short8_t*)(&lsA[0][achunk * 8]) = av;
    __syncthreads();
  }

#pragma unroll
  for (int kt = 0; kt < 8; ++kt) {
    const int cur = kt & 1, nxt = cur ^ 1;

    // ---- issue tile kt+1 (A: global->reg fp32; B: async global->LDS) ----
    f32x4 c0, c1;
    if (kt < 7) {
      c0 = *(const f32x4*)(aptr + (kt + 1) * 32);
      c1 = *(const f32x4*)(aptr + (kt + 1) * 32 + 4);
#pragma unroll
      for (int i = 0; i < 4; ++i) {
        const int cbase = i * 256 + wave * 64;  // wave-uniform LDS base
        __builtin_amdgcn_global_load_lds(
            (const __attribute__((address_space(1))) uint32_t*)(wz + (kt + 1) * 8192 +
                                                                (cbase + lane) * 8),
            (__attribute__((address_space(3))) uint32_t*)(&lsB[nxt][cbase * 8]), 16, 0,
            0);
      }
    }

    // ---- compute tile kt from buffer cur ----
    short8_t af[4], bfrag[4];
#pragma unroll
    for (int mt = 0; mt < 4; ++mt) {
      int c = (mt * 16 + m) * 4 + (q ^ sw);
      af[mt] = *(const short8_t*)(&lsA[cur][c * 8]);
    }
#pragma unroll
    for (int nt = 0; nt < 4; ++nt) {
      int c = (wave * 64 + nt * 16 + m) * 4 + (q ^ sw);
      bfrag[nt] = *(const short8_t*)(&lsB[cur][c * 8]);
    }
#pragma unroll
    for (int mt = 0; mt < 4; ++mt)
#pragma unroll
      for (int nt = 0; nt < 4; ++nt)
        acc[mt][nt] = __builtin_amdgcn_mfma_f32_16x16x32_bf16(af[mt], bfrag[nt],
                                                              acc[mt][nt], 0, 0, 0);

    // ---- finish staging tile kt+1 (convert A after MFMAs), single barrier ----
    if (kt < 7) {
      short8_t av;
      av[0] = (short)f2bf(c0.x); av[1] = (short)f2bf(c0.y);
      av[2] = (short)f2bf(c0.z); av[3] = (short)f2bf(c0.w);
      av[4] = (short)f2bf(c1.x); av[5] = (short)f2bf(c1.y);
      av[6] = (short)f2bf(c1.z); av[7] = (short)f2bf(c1.w);
      *(short8_t*)(&lsA[nxt][achunk * 8]) = av;
      __syncthreads();
    }
  }

  // epilogue: C/D layout col=lane&15, row=quad*4+reg
#pragma unroll
  for (int mt = 0; mt < 4; ++mt) {
#pragma unroll
    for (int nt = 0; nt < 4; ++nt) {
      const int col = wave * 64 + nt * 16 + m;
      const int rowb = m0 + mt * 16 + q * 4;
#pragma unroll
      for (int e = 0; e < 4; ++e) out[(rowb + e) * NN + col] = acc[mt][nt][e];
    }
  }
}

extern "C" void kernel_launch(void* const* d_in, const int* in_sizes, int n_in,
                              void* d_out, int out_size, void* d_ws, size_t ws_size,
                              hipStream_t stream) {
  const float* x = (const float*)d_in[0];
  const float* W = (const float*)d_in[1];
  float* out = (float*)d_out;

  char* ws = (char*)d_ws;
  ushort_t* wz = (ushort_t*)ws;      // 131072 B (bf16 Wz, swizzled)
  float* M = (float*)(ws + 131072);  // 262144 B

  gram_kernel<<<256, 256, 0, stream>>>(W, M);
  power_kernel<<<1, 1024, 0, stream>>>(W, M, wz);
  gemm_kernel<<<BATCH / 64, 256, 0, stream>>>(x, wz, out);
}